// Round 3
// baseline (166.800 us; speedup 1.0000x reference)
//
#include <hip/hip_runtime.h>

#define N_ELEM 95

typedef float f32x4 __attribute__((ext_vector_type(4)));
typedef int   i32x4 __attribute__((ext_vector_type(4)));

__global__ void zbl_reduce_kernel(const float* __restrict__ ws,
                                  float* __restrict__ out,
                                  int n_nodes, int copies) {
    int i = blockIdx.x * blockDim.x + threadIdx.x;
    if (i < n_nodes) {
        float s = 0.0f;
        for (int c = 0; c < copies; ++c) s += ws[(size_t)c * n_nodes + i];
        out[i] = s;
    }
}

__global__ __launch_bounds__(256) void zbl_edge_kernel(
    const int*   __restrict__ z,
    const float* __restrict__ dist,
    const int*   __restrict__ sender,
    const int*   __restrict__ receiver,
    const float* __restrict__ a_factor_p,
    const float* __restrict__ z_power_p,
    const float* __restrict__ coefs,
    const float* __restrict__ exps,
    const float* __restrict__ cradii,
    float*       __restrict__ outbuf,   // copies * n_nodes accumulators
    int n_edges, int n_nodes, int copy_mask)
{
    __shared__ float2 s_tab[N_ELEM];  // {Z^Z_power, covalent_radius}
    __shared__ float  s_coef[4];
    __shared__ float  s_exp[4];
    __shared__ float  s_inv_pref;     // 1 / (a_factor * 0.529)

    const int tid = threadIdx.x;
    if (tid < N_ELEM) {
        float zp = z_power_p[0];
        s_tab[tid] = make_float2(__powf((float)tid, zp), cradii[tid]);
    }
    if (tid < 4) { s_coef[tid] = coefs[tid]; s_exp[tid] = exps[tid]; }
    if (tid == 0) s_inv_pref = 1.0f / (a_factor_p[0] * 0.529f);
    __syncthreads();

    float* __restrict__ acc = outbuf + (size_t)(blockIdx.x & copy_mask) * n_nodes;
    const float inv_pref = s_inv_pref;
    const float c0 = s_coef[0], c1 = s_coef[1], c2 = s_coef[2], c3 = s_coef[3];
    const float e0 = s_exp[0],  e1 = s_exp[1],  e2 = s_exp[2],  e3 = s_exp[3];

    const int n_grp = n_edges >> 3;   // groups of 8 edges
    const int g = blockIdx.x * blockDim.x + tid;

    if (g < n_grp) {
        // streaming loads, non-temporal (keep L2 for the z gathers)
        const f32x4* dp = (const f32x4*)dist;
        const i32x4* sp = (const i32x4*)sender;
        const i32x4* rp = (const i32x4*)receiver;
        const f32x4 dA = __builtin_nontemporal_load(dp + 2 * g);
        const f32x4 dB = __builtin_nontemporal_load(dp + 2 * g + 1);
        const i32x4 sA = __builtin_nontemporal_load(sp + 2 * g);
        const i32x4 sB = __builtin_nontemporal_load(sp + 2 * g + 1);
        const i32x4 rA = __builtin_nontemporal_load(rp + 2 * g);
        const i32x4 rB = __builtin_nontemporal_load(rp + 2 * g + 1);

        float dd[8] = {dA.x, dA.y, dA.z, dA.w, dB.x, dB.y, dB.z, dB.w};
        int   ss[8] = {sA.x, sA.y, sA.z, sA.w, sB.x, sB.y, sB.z, sB.w};
        int   rr[8] = {rA.x, rA.y, rA.z, rA.w, rB.x, rB.y, rB.z, rB.w};

        // issue all 16 gathers before any use (MLP)
        int zu[8], zv[8];
        #pragma unroll
        for (int k = 0; k < 8; ++k) zu[k] = z[ss[k]];
        #pragma unroll
        for (int k = 0; k < 8; ++k) zv[k] = z[rr[k]];

        #pragma unroll
        for (int k = 0; k < 8; ++k) {
            const float d = dd[k];
            const float2 tu = s_tab[zu[k]];
            const float2 tv = s_tab[zv[k]];
            const float rmax = tu.y + tv.y;
            const float t    = __fdividef(d, rmax);
            if (t < 1.0f) {
                const float roa = d * (tu.x + tv.x) * inv_pref;
                const float phi = c0 * __expf(-e0 * roa)
                                + c1 * __expf(-e1 * roa)
                                + c2 * __expf(-e2 * roa)
                                + c3 * __expf(-e3 * roa);
                const float v   = 7.1998f * (float)(zu[k] * zv[k]) * phi
                                * __fdividef(1.0f, d);
                const float t2  = t * t;
                const float t6  = t2 * t2 * t2;
                // p=6: 1 - 28 t^6 + 48 t^7 - 21 t^8
                const float env = 1.0f - t6 * (28.0f - 48.0f * t + 21.0f * t2);
                unsafeAtomicAdd(&acc[rr[k]], v * env);
            }
        }
    } else if (g == n_grp) {
        // scalar tail (n_edges % 8), handled by a single thread
        for (int i = n_grp << 3; i < n_edges; ++i) {
            const float d  = dist[i];
            const int   zu = z[sender[i]];
            const int   rv = receiver[i];
            const int   zv = z[rv];
            const float2 tu = s_tab[zu];
            const float2 tv = s_tab[zv];
            const float rmax = tu.y + tv.y;
            const float t    = __fdividef(d, rmax);
            if (t < 1.0f) {
                const float roa = d * (tu.x + tv.x) * inv_pref;
                const float phi = c0 * __expf(-e0 * roa)
                                + c1 * __expf(-e1 * roa)
                                + c2 * __expf(-e2 * roa)
                                + c3 * __expf(-e3 * roa);
                const float v   = 7.1998f * (float)(zu * zv) * phi
                                * __fdividef(1.0f, d);
                const float t2  = t * t;
                const float t6  = t2 * t2 * t2;
                const float env = 1.0f - t6 * (28.0f - 48.0f * t + 21.0f * t2);
                unsafeAtomicAdd(&acc[rv], v * env);
            }
        }
    }
}

extern "C" void kernel_launch(void* const* d_in, const int* in_sizes, int n_in,
                              void* d_out, int out_size, void* d_ws, size_t ws_size,
                              hipStream_t stream) {
    const int*   z        = (const int*)d_in[0];
    const float* dist     = (const float*)d_in[1];
    const int*   eidx     = (const int*)d_in[2];
    const float* a_factor = (const float*)d_in[3];
    const float* z_power  = (const float*)d_in[4];
    const float* coefs    = (const float*)d_in[5];
    const float* exps     = (const float*)d_in[6];
    const float* cradii   = (const float*)d_in[7];
    float* out = (float*)d_out;

    const int n_edges = in_sizes[1];
    const int n_nodes = out_size;
    const int* sender   = eidx;
    const int* receiver = eidx + n_edges;

    // private accumulator copies in workspace (power of 2, <=16)
    int copies = 1;
    {
        size_t max_copies = ws_size / ((size_t)n_nodes * sizeof(float));
        while (copies * 2 <= (int)max_copies && copies < 16) copies *= 2;
        if (max_copies < 1) copies = 0;
    }

    const int n_grp  = n_edges >> 3;
    const int blocks = (n_grp + 1 + 255) / 256;

    if (copies >= 2) {
        float* ws = (float*)d_ws;
        hipMemsetAsync(ws, 0, (size_t)copies * n_nodes * sizeof(float), stream);
        zbl_edge_kernel<<<blocks, 256, 0, stream>>>(
            z, dist, sender, receiver, a_factor, z_power, coefs, exps, cradii,
            ws, n_edges, n_nodes, copies - 1);
        zbl_reduce_kernel<<<(n_nodes + 255) / 256, 256, 0, stream>>>(
            ws, out, n_nodes, copies);
    } else {
        hipMemsetAsync(out, 0, (size_t)n_nodes * sizeof(float), stream);
        zbl_edge_kernel<<<blocks, 256, 0, stream>>>(
            z, dist, sender, receiver, a_factor, z_power, coefs, exps, cradii,
            out, n_edges, n_nodes, 0);
    }
}